// Round 1
// baseline (173.851 us; speedup 1.0000x reference)
//
#include <hip/hip_runtime.h>
#include <hip/hip_bf16.h>

// Problem constants (from reference)
#define TAPS 901
#define HALF 450

// Conv kernel tiling: 256 threads * 5 outputs each = 1280 outputs/block.
// R=5 chosen so the sliding-window LDS read has lane stride 5 floats
// (gcd(5,32)=1 -> 2 lanes/bank -> conflict-free per m136).
#define CB 256
#define R 5
#define OPB (CB * R)          // 1280
#define TILE 2196             // >= 1275 + 900 + 2 + R + align slack

// ---------------------------------------------------------------------------
// Kernel 1: build the two 901-tap weight vectors + their nonzero bounds.
// bounds = {rot_lo, rot_hi, gauss_lo, gauss_hi} (inclusive)
// ---------------------------------------------------------------------------
__global__ __launch_bounds__(1024) void build_weights(
    const float* __restrict__ lns, const float* __restrict__ lnv,
    float* __restrict__ rot_w, float* __restrict__ gauss_w,
    int* __restrict__ bounds) {
  __shared__ float red[1024];
  __shared__ int sb[4];
  int t = threadIdx.x;
  if (t < 4) sb[t] = (t & 1) ? -1 : TAPS;
  __syncthreads();

  float sigma = 0.01f + expf(lns[0]);
  float vsini = 0.9f + expf(lnv[0]);

  float rv = 0.f, gv = 0.f;
  if (t < TAPS) {
    float g = -4.5f + 0.01f * (float)t;          // linspace(-4.5,4.5,901)
    float x = (299792.458f * g / 10500.0f) / vsini;
    float x2 = fminf(x * x, 1.0f);
    // 0.99999999 rounds to 1.0f in fp32, so the reference's f32 compare is x2<1
    if (x2 < 1.0f) rv = 2.0f * sqrtf(1.0f - x2);
    gv = (1.0f / (sigma * sqrtf(2.0f * 3.1415926654f))) *
         expf(-0.5f * g * g / (sigma * sigma)) * 0.01f;
  }

  red[t] = rv;
  __syncthreads();
  for (int s = 512; s > 0; s >>= 1) {
    if (t < s) red[t] += red[t + s];
    __syncthreads();
  }
  float rsum = red[0];

  if (t < TAPS) {
    float rw = rv / rsum;
    rot_w[t] = rw;
    gauss_w[t] = gv;
    if (rw != 0.0f) { atomicMin(&sb[0], t); atomicMax(&sb[1], t); }
    // taps below 1e-10 contribute < 901e-10 total (flux in [0,1]) -- skip them
    if (fabsf(gv) > 1e-10f) { atomicMin(&sb[2], t); atomicMax(&sb[3], t); }
  }
  __syncthreads();
  if (t == 0) {
    int rlo = sb[0], rhi = sb[1], glo = sb[2], ghi = sb[3];
    if (rhi < rlo) { rlo = HALF; rhi = HALF; }
    if (ghi < glo) { glo = HALF; ghi = HALF; }
    bounds[0] = rlo; bounds[1] = rhi; bounds[2] = glo; bounds[3] = ghi;
  }
}

// ---------------------------------------------------------------------------
// Conv kernel (templated): out[i] = sum_k w[k] * in[i + k - 450], zero-padded.
// SCATTER=false: write conv result to out[] (intermediate rot pass).
// SCATTER=true : atomicAdd run-merged partial sums into out[] (= per-bin sums)
//                using the sorted segment_ids (fused conv2 + segment_sum).
// ---------------------------------------------------------------------------
template <int BIDX, bool SCATTER>
__global__ __launch_bounds__(CB) void conv_k(
    const float* __restrict__ in, float* __restrict__ out,
    const float* __restrict__ w, const int* __restrict__ bounds,
    const int* __restrict__ ids, int n) {
  __shared__ __align__(16) float lds[TILE];
  const int tid = threadIdx.x;
  const int blockBase = blockIdx.x * OPB;
  const int klo = __builtin_amdgcn_readfirstlane(bounds[BIDX]);
  const int khi = __builtin_amdgcn_readfirstlane(bounds[BIDX + 1]);

  // Stage: lds[j] = in[blockBase - 452 + j]  (the -452 keeps float4 alignment)
  const int jlo = klo & ~3;
  const int jend = ((255 * R + khi + 2 + R + 1) + 3) & ~3;  // exclusive
  for (int j = jlo + tid * 4; j < jend; j += CB * 4) {
    int g = blockBase - 452 + j;
    float4 v;
    if (g >= 0 && g + 3 < n) {
      v = *reinterpret_cast<const float4*>(in + g);
    } else {
      v.x = (g     >= 0 && g     < n) ? in[g]     : 0.f;
      v.y = (g + 1 >= 0 && g + 1 < n) ? in[g + 1] : 0.f;
      v.z = (g + 2 >= 0 && g + 2 < n) ? in[g + 2] : 0.f;
      v.w = (g + 3 >= 0 && g + 3 < n) ? in[g + 3] : 0.f;
    }
    *reinterpret_cast<float4*>(&lds[j]) = v;
  }
  __syncthreads();

  // Sliding-window conv: thread owns outputs base..base+R-1 (contiguous).
  // Invariant at tap t: win[(t+r)%R] == lds[idx0 + t + r]
  const int idx0 = tid * R + klo + 2;
  float win[R];
#pragma unroll
  for (int r = 0; r < R; ++r) win[r] = lds[idx0 + r];
  float acc[R] = {0.f, 0.f, 0.f, 0.f, 0.f};

  const int nk = khi - klo + 1;
  const float* wp = w + klo;  // klo is wave-uniform -> wp[kk+u] scalarizes
  int kk = 0;
  for (; kk + R <= nk; kk += R) {
#pragma unroll
    for (int u = 0; u < R; ++u) {
      float wk = wp[kk + u];
#pragma unroll
      for (int r = 0; r < R; ++r)
        acc[r] = fmaf(wk, win[(u + r) % R], acc[r]);
      win[u] = lds[idx0 + kk + u + R];  // refill oldest slot ((kk+u)%R == u)
    }
  }
  for (; kk < nk; ++kk) {
    float wk = wp[kk];
#pragma unroll
    for (int r = 0; r < R; ++r)
      acc[r] = fmaf(wk, lds[idx0 + kk + r], acc[r]);
  }

  const int base = blockBase + tid * R;
  if (!SCATTER) {
    if (base + R <= n) {
#pragma unroll
      for (int r = 0; r < R; ++r) out[base + r] = acc[r];
    } else {
#pragma unroll
      for (int r = 0; r < R; ++r)
        if (base + r < n) out[base + r] = acc[r];
    }
  } else {
    int cnt = n - base;
    cnt = cnt < R ? cnt : R;
    if (cnt > 0) {
      int cur = ids[base];
      float run = acc[0];
      for (int r = 1; r < cnt; ++r) {
        int id2 = ids[base + r];
        if (id2 == cur) {
          run += acc[r];
        } else {
          atomicAdd(&out[cur], run);
          cur = id2;
          run = acc[r];
        }
      }
      atomicAdd(&out[cur], run);
    }
  }
}

// ---------------------------------------------------------------------------
// Kernel 3: per-bin mean. counts recovered via binary search on sorted ids.
// Output is bins 1..nbins-2 (reference's [1:-1]).
// ---------------------------------------------------------------------------
__global__ void seg_mean(const float* __restrict__ sums,
                         const int* __restrict__ ids, int n,
                         float* __restrict__ out, int out_n) {
  int gid = blockIdx.x * blockDim.x + threadIdx.x;
  if (gid >= out_n) return;
  int b = gid + 1;
  int lo = 0, hi = n;
  while (lo < hi) { int m = (lo + hi) >> 1; if (ids[m] < b) lo = m + 1; else hi = m; }
  int start = lo;
  hi = n;
  while (lo < hi) { int m = (lo + hi) >> 1; if (ids[m] < b + 1) lo = m + 1; else hi = m; }
  int c = lo - start;
  float mean = sums[b] / (float)(c > 1 ? c : 1);
  out[gid] = fminf(fmaxf(mean, 0.f), 1.f);
}

// ---------------------------------------------------------------------------
extern "C" void kernel_launch(void* const* d_in, const int* in_sizes, int n_in,
                              void* d_out, int out_size, void* d_ws,
                              size_t ws_size, hipStream_t stream) {
  const float* flux = (const float*)d_in[0];
  const float* lns  = (const float*)d_in[1];
  const float* lnv  = (const float*)d_in[2];
  const int*   ids  = (const int*)d_in[3];
  float* out = (float*)d_out;
  const int n = in_sizes[0];
  const int nbins = out_size + 2;

  // ws layout (floats): rot_w[1024] | gauss_w[1024] | bounds[...pad to 4096]
  //                     | rot_out[n] | sums[nbins]        (~18.3 MB total)
  float* ws      = (float*)d_ws;
  float* rot_w   = ws;
  float* gauss_w = ws + 1024;
  int*   bounds  = (int*)(ws + 2048);
  float* rot_out = ws + 4096;
  float* sums    = ws + 4096 + n;

  build_weights<<<1, 1024, 0, stream>>>(lns, lnv, rot_w, gauss_w, bounds);
  hipMemsetAsync(sums, 0, (size_t)nbins * sizeof(float), stream);

  const int nblk = (n + OPB - 1) / OPB;
  conv_k<0, false><<<nblk, CB, 0, stream>>>(flux, rot_out, rot_w, bounds,
                                            nullptr, n);
  conv_k<2, true><<<nblk, CB, 0, stream>>>(rot_out, sums, gauss_w, bounds,
                                           ids, n);
  seg_mean<<<(out_size + 255) / 256, 256, 0, stream>>>(sums, ids, n, out,
                                                       out_size);
}